// Round 10
// baseline (681.647 us; speedup 1.0000x reference)
//
#include <hip/hip_runtime.h>
#include <hip/hip_bf16.h>

// PointCloudNetPersistencePrediction — round 10: kill LDS bank conflicts.
// R9 post-mortem: flat vs R8. Diagnosis: xj reads put the 4 quads exactly
// 128 B apart -> all four b128 reads hit the same bank group (4-way, x1.58,
// m136). Fix: padded LDS layout addr(e) = e + (e>>3) (float4 units) ->
// quads land 144 B apart = bank offsets {0,4,8,12}: conflict-free.
// Shape unchanged from R9: 512 thr = 8 K-waves, 4 m-subtiles, M=64, grid 512.

#define NN 2048
#define NPAIR 16

typedef _Float16 half8 __attribute__((ext_vector_type(8)));
typedef __fp16   fp16x2 __attribute__((ext_vector_type(2)));
typedef float f32x4 __attribute__((ext_vector_type(4)));

#define C2F 0.28853900817779268f   //  0.2 * log2(e)
#define CWF -0.14426950408889634f  // -0.1 * log2(e)
#define L2T -3.3219280948873623f   //  log2(0.1): w<0.1 <=> arg<L2T

// padded float4 index: one pad slot per 8 entries (breaks 128B quad stride)
#define PIDX(e) ((e) + ((e) >> 3))

// ---- init: Xs fp32 [p][i][{x,y,z,q}]; XT fp16 [p][16][2048], row3 = ones ----
__global__ __launch_bounds__(256) void init_k(const float* __restrict__ pc,
                                              const float* __restrict__ alphas,
                                              float* __restrict__ Xs,
                                              _Float16* __restrict__ XT) {
    int gid = blockIdx.x * 256 + threadIdx.x;
    if (gid >= NPAIR * NN) return;
    int p = gid >> 11, i = gid & (NN - 1);
    int b = p >> 2, k = p & 3;
    const float* pcr = pc + ((size_t)b * NN + i) * 3;
    const float* al  = alphas + k * 3;
    float x = pcr[0] * al[0], y = pcr[1] * al[1], z = pcr[2] * al[2];
    float4 o; o.x = x; o.y = y; o.z = z; o.w = CWF * (x * x + y * y + z * z);
    ((float4*)Xs)[gid] = o;
    _Float16* xt = XT + (size_t)p * 16 * NN + i;
    xt[0 * NN] = (_Float16)x;
    xt[1 * NN] = (_Float16)y;
    xt[2 * NN] = (_Float16)z;
    xt[3 * NN] = (_Float16)1.0f;          // ones column -> deg via MFMA
#pragma unroll
    for (int n = 4; n < 16; ++n) xt[n * NN] = (_Float16)0.f;
}

// xi.xyz pre-scaled by C2F; xj raw. w = exp2(qi+qj+dot), 0 if arg<log2(0.1).
__device__ __forceinline__ float evalw(float4 xi, float4 xj) {
    float t = xi.w + xj.w;
    t = fmaf(xi.x, xj.x, t);
    t = fmaf(xi.y, xj.y, t);
    t = fmaf(xi.z, xj.z, t);
    float w = __builtin_amdgcn_exp2f(t);
    return (t < L2T) ? 0.f : w;
}

// ---- fused apply: Ct = f16(0.5*Bt + ihd (x) (W@Bt^T)^T), W recomputed ----
// block = 512 thr = 8 waves, each wave = K-chunk 256; lane owns 4 m-subtiles
// (M=64 rows/block). Grid (32,16)=512 blocks. Red LDS aliases padded X stage.
template<bool FIRST>
__global__ __launch_bounds__(512, 4) void fused_apply_k(const float* __restrict__ Xs,
                                                        float* __restrict__ ihd,
                                                        const _Float16* __restrict__ Bt,
                                                        _Float16* __restrict__ Ct,
                                                        float* __restrict__ lvl,
                                                        int t) {
    __shared__ __align__(16) float smem[9216];     // 36 KB: padded X / red(32KB)
    const int tid  = threadIdx.x;
    const int lane = tid & 63;
    const int wv   = tid >> 6;                     // K-group 0..7
    const int p    = blockIdx.y;
    const int m0   = blockIdx.x * 64;
    const int idx16 = lane & 15, quad = lane >> 4;

    // stage whole pair X into padded LDS (2048 float4, 4 per thread)
    {
        const float4* src = (const float4*)(Xs + (size_t)p * NN * 4);
        float4* dst = (float4*)smem;
#pragma unroll
        for (int c = 0; c < 4; ++c) {
            int e = tid + c * 512;
            dst[PIDX(e)] = src[e];
        }
    }
    __syncthreads();

    float4 xi[4];
#pragma unroll
    for (int s = 0; s < 4; ++s) {
        float4 v = ((const float4*)smem)[PIDX(m0 + s * 16 + idx16)];
        xi[s].x = C2F * v.x; xi[s].y = C2F * v.y; xi[s].z = C2F * v.z; xi[s].w = v.w;
    }

    const _Float16* bp = Bt + ((size_t)p * 16 + idx16) * NN + wv * 256 + quad * 8;
    f32x4 acc[4] = {{0.f,0.f,0.f,0.f},{0.f,0.f,0.f,0.f},
                    {0.f,0.f,0.f,0.f},{0.f,0.f,0.f,0.f}};

    for (int kc = 0; kc < 8; ++kc) {
        const int kb = wv * 256 + kc * 32 + quad * 8;      // float4 entry
        const int kpad = kb + (kb >> 3);                   // padded base (2jp<8 safe)
        half8 bf = *(const half8*)(bp + kc * 32);
        union { fp16x2 h2[4]; half8 h8; } af[4];
#pragma unroll
        for (int jp = 0; jp < 4; ++jp) {
            float4 xj0 = ((const float4*)smem)[kpad + 2 * jp];
            float4 xj1 = ((const float4*)smem)[kpad + 2 * jp + 1];
#pragma unroll
            for (int s = 0; s < 4; ++s)
                af[s].h2[jp] = __builtin_amdgcn_cvt_pkrtz(evalw(xi[s], xj0),
                                                          evalw(xi[s], xj1));
        }
#pragma unroll
        for (int s = 0; s < 4; ++s)
            acc[s] = __builtin_amdgcn_mfma_f32_16x16x32_f16(af[s].h8, bf, acc[s], 0, 0, 0);
    }

    // cross-wave K-reduce: red[kg 8][s 4][256] aliased over X stage
    __syncthreads();
#pragma unroll
    for (int s = 0; s < 4; ++s)
        *(f32x4*)&smem[wv * 1024 + s * 256 + lane * 4] = acc[s];
    __syncthreads();

    // 2 outputs/thread: o -> n = o&15, rloc = o>>4 (s = rloc>>4, mloc = rloc&15)
    const float* ihp = ihd + p * NN;
#pragma unroll
    for (int oo = 0; oo < 2; ++oo) {
        const int o = tid + oo * 512;
        const int n = o & 15, rloc = o >> 4;
        const int s = rloc >> 4, mloc = rloc & 15;
        const int base = s * 256 + (mloc >> 2) * 64 + (mloc & 3);
        float sum = 0.f;
#pragma unroll
        for (int g = 0; g < 8; ++g) sum += smem[g * 1024 + base + n * 4];
        const int row = m0 + rloc;
        float ih;
        if (FIRST) {
            float deg = 0.f;
#pragma unroll
            for (int g = 0; g < 8; ++g) deg += smem[g * 1024 + base + 12];  // col 3
            ih = 0.5f / deg;
            if (n == 3) ihd[p * NN + row] = ih;
        } else {
            ih = ihp[row];
        }
        float cv = (float)Bt[((size_t)p * 16 + n) * NN + row];
        float out = 0.5f * cv + ih * sum;
        Ct[((size_t)p * 16 + n) * NN + row] = (_Float16)out;
        if (lvl) lvl[(((size_t)p * 5 + t) * 16 + n) * NN + row] = out;
    }
}

// ---- build UT fp16 [p][16][2048]: rows 0-11 = |psi_0..3 X|, 12-15 = 0 ----
__global__ __launch_bounds__(256) void buildU_k(const float* __restrict__ Xs,
                                                const float* __restrict__ LT1,
                                                _Float16* __restrict__ UT) {
    int p = blockIdx.y;
    int m = blockIdx.x * 256 + threadIdx.x;
    const float* lp = LT1 + (size_t)p * 5 * 16 * NN;
    float4 xr = ((const float4*)Xs)[p * NN + m];
    float prev[3] = {xr.x, xr.y, xr.z};
    _Float16* ut = UT + (size_t)p * 16 * NN + m;
#pragma unroll
    for (int jw = 0; jw < 4; ++jw) {
#pragma unroll
        for (int c = 0; c < 3; ++c) {
            float nx = lp[((size_t)jw * 16 + c) * NN + m];
            ut[(3 * jw + c) * NN] = (_Float16)fabsf(prev[c] - nx);
            prev[c] = nx;
        }
    }
#pragma unroll
    for (int n = 12; n < 16; ++n) ut[n * NN] = (_Float16)0.f;
}

// ---- final mean over N of 48 features (levels [p][t][n][m]) ----
__global__ __launch_bounds__(64) void reduce_k(const float* __restrict__ Xs,
                                               const float* __restrict__ LT1,
                                               const float* __restrict__ LT2,
                                               float* __restrict__ out) {
    int f = blockIdx.x, p = blockIdx.y, lane = threadIdx.x;
    const float* l1 = LT1 + (size_t)p * 5 * 16 * NN;
    const float* l2 = LT2 + (size_t)p * 5 * 16 * NN;
    float s = 0.f;
    for (int m = lane; m < NN; m += 64) {
        float v;
        if (f < 3) {
            v = l1[((size_t)4 * 16 + f) * NN + m];
        } else if (f < 18) {
            int j = (f - 3) / 3, c = (f - 3) % 3;
            float a = (j == 0) ? Xs[((size_t)p * NN + m) * 4 + c]
                               : l1[((size_t)(j - 1) * 16 + c) * NN + m];
            float b = l1[((size_t)j * 16 + c) * NN + m];
            v = fabsf(a - b);
        } else {
            int gg = f - 18, j2, uc;
            if (gg < 3)       { j2 = 1; uc = gg; }
            else if (gg < 9)  { j2 = 2; uc = gg - 3; }
            else if (gg < 18) { j2 = 3; uc = gg - 9; }
            else              { j2 = 4; uc = gg - 18; }
            v = fabsf(l2[((size_t)(j2 - 1) * 16 + uc) * NN + m]
                    - l2[((size_t)j2 * 16 + uc) * NN + m]);
        }
        s += v;
    }
#pragma unroll
    for (int off = 32; off > 0; off >>= 1) s += __shfl_down(s, off, 64);
    if (lane == 0) out[p * 48 + f] = s * (1.0f / NN);
}

extern "C" void kernel_launch(void* const* d_in, const int* in_sizes, int n_in,
                              void* d_out, int out_size, void* d_ws, size_t ws_size,
                              hipStream_t stream) {
    const float* pc     = (const float*)d_in[0];
    const float* alphas = (const float*)d_in[1];
    float* outp = (float*)d_out;

    char* base = (char*)d_ws;
    size_t off = 0;
    auto carve = [&](size_t bytes) -> void* {
        void* r = base + off;
        off = (off + bytes + 255) & ~(size_t)255;
        return r;
    };
    float*     Xs  = (float*)carve((size_t)NPAIR * NN * 4 * sizeof(float));
    float*     ihd = (float*)carve((size_t)NPAIR * NN * sizeof(float));
    _Float16*  XT  = (_Float16*)carve((size_t)NPAIR * 16 * NN * 2);
    _Float16*  UT  = (_Float16*)carve((size_t)NPAIR * 16 * NN * 2);
    _Float16*  pA  = (_Float16*)carve((size_t)NPAIR * 16 * NN * 2);
    _Float16*  pB  = (_Float16*)carve((size_t)NPAIR * 16 * NN * 2);
    float*     LT1 = (float*)carve((size_t)NPAIR * 5 * 16 * NN * sizeof(float));
    float*     LT2 = (float*)carve((size_t)NPAIR * 5 * 16 * NN * sizeof(float));

    dim3 gridA(NN / 64, NPAIR);   // 32 x 16 = 512 blocks

    init_k<<<dim3((NPAIR * NN) / 256), 256, 0, stream>>>(pc, alphas, Xs, XT);

    // bank 1: B = XT (col3 = ones -> apply#1 computes deg/ihd itself)
    {
        const _Float16* cur = XT;
        int slot = 0;
        for (int step = 1; step <= 16; ++step) {
            bool sv = (step == 1 || step == 2 || step == 4 || step == 8 || step == 16);
            _Float16* o = (cur == pA) ? pB : pA;
            float* lv = sv ? LT1 : nullptr;
            if (step == 1)
                fused_apply_k<true><<<gridA, 512, 0, stream>>>(Xs, ihd, cur, o, lv, slot);
            else
                fused_apply_k<false><<<gridA, 512, 0, stream>>>(Xs, ihd, cur, o, lv, slot);
            if (sv) ++slot;
            cur = o;
        }
    }

    buildU_k<<<dim3(NN / 256, NPAIR), 256, 0, stream>>>(Xs, LT1, UT);

    // bank 2: B = UT
    {
        const _Float16* cur = UT;
        int slot = 0;
        for (int step = 1; step <= 16; ++step) {
            bool sv = (step == 1 || step == 2 || step == 4 || step == 8 || step == 16);
            _Float16* o = (cur == pA) ? pB : pA;
            fused_apply_k<false><<<gridA, 512, 0, stream>>>(Xs, ihd, cur, o,
                                                            sv ? LT2 : nullptr, slot);
            if (sv) ++slot;
            cur = o;
        }
    }

    reduce_k<<<dim3(48, NPAIR), 64, 0, stream>>>(Xs, LT1, LT2, outp);
}

// Round 11
// 567.138 us; speedup vs baseline: 1.2019x; 1.2019x over previous
//
#include <hip/hip_runtime.h>
#include <hip/hip_bf16.h>

// PointCloudNetPersistencePrediction — round 11: packed-fp16 eval pipeline.
// R9 (DS instr halved) and R10 (bank conflicts removed) were both FLAT ->
// applies are VALU-issue-port bound on the w-eval (incl. quarter-rate exp).
// Fix: v_pk_* math on fp16 j-pairs (2 evals/instr): t'=qi'+qj+C2F*xi.xj via
// pk_add+3 pk_fma, 10w=exp2_2f16(t') (10=2^3.32 folded into epilogue's ih),
// theta=min(max(2048*t',0),1), af=w*theta. ~10 instr/2 evals vs 15; DS reads
// halve (b128 per 2 j). Row-normalization cancels common-mode qi rounding.

#define NN 2048
#define NPAIR 16

typedef _Float16 half8 __attribute__((ext_vector_type(8)));
typedef _Float16 f16x2 __attribute__((ext_vector_type(2)));
typedef float f32x4 __attribute__((ext_vector_type(4)));

extern "C" __device__ f16x2 __ocml_exp2_2f16(f16x2);   // packed v_exp_f16

#define C2F 0.28853900817779268f   //  0.2 * log2(e)
#define CWF -0.14426950408889634f  // -0.1 * log2(e)
#define NL2T 3.3219280948873623f   // -log2(0.1); qi' = qi + NL2T

// ---- init: Xs fp32 [p][i][{x,y,z,q}]; XT fp16 [p][16][2048], row3 = ones ----
__global__ __launch_bounds__(256) void init_k(const float* __restrict__ pc,
                                              const float* __restrict__ alphas,
                                              float* __restrict__ Xs,
                                              _Float16* __restrict__ XT) {
    int gid = blockIdx.x * 256 + threadIdx.x;
    if (gid >= NPAIR * NN) return;
    int p = gid >> 11, i = gid & (NN - 1);
    int b = p >> 2, k = p & 3;
    const float* pcr = pc + ((size_t)b * NN + i) * 3;
    const float* al  = alphas + k * 3;
    float x = pcr[0] * al[0], y = pcr[1] * al[1], z = pcr[2] * al[2];
    float4 o; o.x = x; o.y = y; o.z = z; o.w = CWF * (x * x + y * y + z * z);
    ((float4*)Xs)[gid] = o;
    _Float16* xt = XT + (size_t)p * 16 * NN + i;
    xt[0 * NN] = (_Float16)x;
    xt[1 * NN] = (_Float16)y;
    xt[2 * NN] = (_Float16)z;
    xt[3 * NN] = (_Float16)1.0f;          // ones column -> deg via MFMA
#pragma unroll
    for (int n = 4; n < 16; ++n) xt[n * NN] = (_Float16)0.f;
}

// ---- pack_k: Xp16[p][e] = {x2,y2,z2,q2} fp16 pairs of rows (2e, 2e+1) ----
__global__ __launch_bounds__(256) void pack_k(const float* __restrict__ Xs,
                                              float* __restrict__ Xp) {
    int gid = blockIdx.x * 256 + threadIdx.x;      // p*1024 + e
    if (gid >= NPAIR * 1024) return;
    float4 a = ((const float4*)Xs)[2 * gid];
    float4 b = ((const float4*)Xs)[2 * gid + 1];
    union { f16x2 h[4]; float4 f; } o;
    o.h[0] = (f16x2){(_Float16)a.x, (_Float16)b.x};
    o.h[1] = (f16x2){(_Float16)a.y, (_Float16)b.y};
    o.h[2] = (f16x2){(_Float16)a.z, (_Float16)b.z};
    o.h[3] = (f16x2){(_Float16)a.w, (_Float16)b.w};
    ((float4*)Xp)[gid] = o.f;
}

// ---- fused apply: Ct = f16(0.5*Bt + ihd (x) (W@Bt^T)^T), W recomputed ----
// block = 512 thr = 8 waves (K-chunk 256 each); lane owns 4 m-subtiles.
// Fragments hold 10*w; epilogue uses 0.1*ih (exact fold via 2^3.32=10).
template<bool FIRST>
__global__ __launch_bounds__(512, 4) void fused_apply_k(const float* __restrict__ Xs,
                                                        const float* __restrict__ Xp,
                                                        float* __restrict__ ihd,
                                                        const _Float16* __restrict__ Bt,
                                                        _Float16* __restrict__ Ct,
                                                        float* __restrict__ lvl,
                                                        int t) {
    __shared__ __align__(16) float smem[8192];     // 16KB packed X stage / 32KB red
    const int tid  = threadIdx.x;
    const int lane = tid & 63;
    const int wv   = tid >> 6;                     // K-group 0..7
    const int p    = blockIdx.y;
    const int m0   = blockIdx.x * 64;
    const int idx16 = lane & 15, quad = lane >> 4;

    // stage packed X[p] into LDS: 1024 float4 entries (2 per thread)
    {
        const float4* src = (const float4*)(Xp + (size_t)p * 1024 * 4);
        float4* dst = (float4*)smem;
        dst[tid]       = src[tid];
        dst[tid + 512] = src[tid + 512];
    }
    __syncthreads();

    // per-lane row constants (fp16 broadcast pairs), from fp32 Xs
    f16x2 qi2[4], xx2[4], xy2[4], xz2[4];
#pragma unroll
    for (int s = 0; s < 4; ++s) {
        float4 v = *(const float4*)(Xs + ((size_t)p * NN + m0 + s * 16 + idx16) * 4);
        _Float16 q = (_Float16)(v.w + NL2T);
        _Float16 x = (_Float16)(C2F * v.x);
        _Float16 y = (_Float16)(C2F * v.y);
        _Float16 z = (_Float16)(C2F * v.z);
        qi2[s] = (f16x2){q, q};
        xx2[s] = (f16x2){x, x};
        xy2[s] = (f16x2){y, y};
        xz2[s] = (f16x2){z, z};
    }
    const f16x2 K2 = (f16x2){(_Float16)2048.f, (_Float16)2048.f};
    const f16x2 Z2 = (f16x2){(_Float16)0.f, (_Float16)0.f};
    const f16x2 O2 = (f16x2){(_Float16)1.f, (_Float16)1.f};

    const _Float16* bp = Bt + ((size_t)p * 16 + idx16) * NN + wv * 256 + quad * 8;
    f32x4 acc[4] = {{0.f,0.f,0.f,0.f},{0.f,0.f,0.f,0.f},
                    {0.f,0.f,0.f,0.f},{0.f,0.f,0.f,0.f}};

    for (int kc = 0; kc < 8; ++kc) {
        const int pb = wv * 128 + kc * 16 + quad * 4;  // j-pair entry base
        half8 bf = *(const half8*)(bp + kc * 32);
        union { f16x2 h2[4]; half8 h8; } af[4];
#pragma unroll
        for (int jp = 0; jp < 4; ++jp) {
            union { float4 f; f16x2 h[4]; } e;
            e.f = ((const float4*)smem)[pb + jp];      // {x2,y2,z2,q2} for 2 j
#pragma unroll
            for (int s = 0; s < 4; ++s) {
                f16x2 tv = qi2[s] + e.h[3];
                tv = __builtin_elementwise_fma(xx2[s], e.h[0], tv);
                tv = __builtin_elementwise_fma(xy2[s], e.h[1], tv);
                tv = __builtin_elementwise_fma(xz2[s], e.h[2], tv);
                f16x2 w10 = __ocml_exp2_2f16(tv);      // = 10*w (2^3.32 fold)
                f16x2 th = __builtin_elementwise_min(
                               __builtin_elementwise_max(tv * K2, Z2), O2);
                af[s].h2[jp] = w10 * th;
            }
        }
#pragma unroll
        for (int s = 0; s < 4; ++s)
            acc[s] = __builtin_amdgcn_mfma_f32_16x16x32_f16(af[s].h8, bf, acc[s], 0, 0, 0);
    }

    // cross-wave K-reduce: red[kg 8][s 4][256] aliased over stage
    __syncthreads();
#pragma unroll
    for (int s = 0; s < 4; ++s)
        *(f32x4*)&smem[wv * 1024 + s * 256 + lane * 4] = acc[s];
    __syncthreads();

    // 2 outputs/thread: o -> n = o&15, rloc = o>>4
    const float* ihp = ihd + p * NN;
#pragma unroll
    for (int oo = 0; oo < 2; ++oo) {
        const int o = tid + oo * 512;
        const int n = o & 15, rloc = o >> 4;
        const int s = rloc >> 4, mloc = rloc & 15;
        const int base = s * 256 + (mloc >> 2) * 64 + (mloc & 3);
        float sum = 0.f;                               // = 10 * (W@B) element
#pragma unroll
        for (int g = 0; g < 8; ++g) sum += smem[g * 1024 + base + n * 4];
        const int row = m0 + rloc;
        float ihEff;
        if (FIRST) {
            float deg10 = 0.f;                         // = 10 * deg
#pragma unroll
            for (int g = 0; g < 8; ++g) deg10 += smem[g * 1024 + base + 12];
            float ih = 5.0f / deg10;                   // = 0.5/deg
            if (n == 3) ihd[p * NN + row] = ih;
            ihEff = 0.1f * ih;
        } else {
            ihEff = 0.1f * ihp[row];
        }
        float cv = (float)Bt[((size_t)p * 16 + n) * NN + row];
        float out = 0.5f * cv + ihEff * sum;
        Ct[((size_t)p * 16 + n) * NN + row] = (_Float16)out;
        if (lvl) lvl[(((size_t)p * 5 + t) * 16 + n) * NN + row] = out;
    }
}

// ---- build UT fp16 [p][16][2048]: rows 0-11 = |psi_0..3 X|, 12-15 = 0 ----
__global__ __launch_bounds__(256) void buildU_k(const float* __restrict__ Xs,
                                                const float* __restrict__ LT1,
                                                _Float16* __restrict__ UT) {
    int p = blockIdx.y;
    int m = blockIdx.x * 256 + threadIdx.x;
    const float* lp = LT1 + (size_t)p * 5 * 16 * NN;
    float4 xr = ((const float4*)Xs)[p * NN + m];
    float prev[3] = {xr.x, xr.y, xr.z};
    _Float16* ut = UT + (size_t)p * 16 * NN + m;
#pragma unroll
    for (int jw = 0; jw < 4; ++jw) {
#pragma unroll
        for (int c = 0; c < 3; ++c) {
            float nx = lp[((size_t)jw * 16 + c) * NN + m];
            ut[(3 * jw + c) * NN] = (_Float16)fabsf(prev[c] - nx);
            prev[c] = nx;
        }
    }
#pragma unroll
    for (int n = 12; n < 16; ++n) ut[n * NN] = (_Float16)0.f;
}

// ---- final mean over N of 48 features (levels [p][t][n][m]) ----
__global__ __launch_bounds__(64) void reduce_k(const float* __restrict__ Xs,
                                               const float* __restrict__ LT1,
                                               const float* __restrict__ LT2,
                                               float* __restrict__ out) {
    int f = blockIdx.x, p = blockIdx.y, lane = threadIdx.x;
    const float* l1 = LT1 + (size_t)p * 5 * 16 * NN;
    const float* l2 = LT2 + (size_t)p * 5 * 16 * NN;
    float s = 0.f;
    for (int m = lane; m < NN; m += 64) {
        float v;
        if (f < 3) {
            v = l1[((size_t)4 * 16 + f) * NN + m];
        } else if (f < 18) {
            int j = (f - 3) / 3, c = (f - 3) % 3;
            float a = (j == 0) ? Xs[((size_t)p * NN + m) * 4 + c]
                               : l1[((size_t)(j - 1) * 16 + c) * NN + m];
            float b = l1[((size_t)j * 16 + c) * NN + m];
            v = fabsf(a - b);
        } else {
            int gg = f - 18, j2, uc;
            if (gg < 3)       { j2 = 1; uc = gg; }
            else if (gg < 9)  { j2 = 2; uc = gg - 3; }
            else if (gg < 18) { j2 = 3; uc = gg - 9; }
            else              { j2 = 4; uc = gg - 18; }
            v = fabsf(l2[((size_t)(j2 - 1) * 16 + uc) * NN + m]
                    - l2[((size_t)j2 * 16 + uc) * NN + m]);
        }
        s += v;
    }
#pragma unroll
    for (int off = 32; off > 0; off >>= 1) s += __shfl_down(s, off, 64);
    if (lane == 0) out[p * 48 + f] = s * (1.0f / NN);
}

extern "C" void kernel_launch(void* const* d_in, const int* in_sizes, int n_in,
                              void* d_out, int out_size, void* d_ws, size_t ws_size,
                              hipStream_t stream) {
    const float* pc     = (const float*)d_in[0];
    const float* alphas = (const float*)d_in[1];
    float* outp = (float*)d_out;

    char* base = (char*)d_ws;
    size_t off = 0;
    auto carve = [&](size_t bytes) -> void* {
        void* r = base + off;
        off = (off + bytes + 255) & ~(size_t)255;
        return r;
    };
    float*     Xs  = (float*)carve((size_t)NPAIR * NN * 4 * sizeof(float));
    float*     Xp  = (float*)carve((size_t)NPAIR * 1024 * 4 * sizeof(float));
    float*     ihd = (float*)carve((size_t)NPAIR * NN * sizeof(float));
    _Float16*  XT  = (_Float16*)carve((size_t)NPAIR * 16 * NN * 2);
    _Float16*  UT  = (_Float16*)carve((size_t)NPAIR * 16 * NN * 2);
    _Float16*  pA  = (_Float16*)carve((size_t)NPAIR * 16 * NN * 2);
    _Float16*  pB  = (_Float16*)carve((size_t)NPAIR * 16 * NN * 2);
    float*     LT1 = (float*)carve((size_t)NPAIR * 5 * 16 * NN * sizeof(float));
    float*     LT2 = (float*)carve((size_t)NPAIR * 5 * 16 * NN * sizeof(float));

    dim3 gridA(NN / 64, NPAIR);   // 32 x 16 = 512 blocks

    init_k<<<dim3((NPAIR * NN) / 256), 256, 0, stream>>>(pc, alphas, Xs, XT);
    pack_k<<<dim3((NPAIR * 1024) / 256), 256, 0, stream>>>(Xs, Xp);

    // bank 1: B = XT (col3 = ones -> apply#1 computes deg/ihd itself)
    {
        const _Float16* cur = XT;
        int slot = 0;
        for (int step = 1; step <= 16; ++step) {
            bool sv = (step == 1 || step == 2 || step == 4 || step == 8 || step == 16);
            _Float16* o = (cur == pA) ? pB : pA;
            float* lv = sv ? LT1 : nullptr;
            if (step == 1)
                fused_apply_k<true><<<gridA, 512, 0, stream>>>(Xs, Xp, ihd, cur, o, lv, slot);
            else
                fused_apply_k<false><<<gridA, 512, 0, stream>>>(Xs, Xp, ihd, cur, o, lv, slot);
            if (sv) ++slot;
            cur = o;
        }
    }

    buildU_k<<<dim3(NN / 256, NPAIR), 256, 0, stream>>>(Xs, LT1, UT);

    // bank 2: B = UT
    {
        const _Float16* cur = UT;
        int slot = 0;
        for (int step = 1; step <= 16; ++step) {
            bool sv = (step == 1 || step == 2 || step == 4 || step == 8 || step == 16);
            _Float16* o = (cur == pA) ? pB : pA;
            fused_apply_k<false><<<gridA, 512, 0, stream>>>(Xs, Xp, ihd, cur, o,
                                                            sv ? LT2 : nullptr, slot);
            if (sv) ++slot;
            cur = o;
        }
    }

    reduce_k<<<dim3(48, NPAIR), 64, 0, stream>>>(Xs, LT1, LT2, outp);
}

// Round 12
// 564.621 us; speedup vs baseline: 1.2073x; 1.0045x over previous
//
#include <hip/hip_runtime.h>
#include <hip/hip_bf16.h>

// PointCloudNetPersistencePrediction — round 12: fold threshold into exp arg.
// R11 matched (682->567us, VALU-port bound confirmed). Remaining hot loop:
// 1024 pk + 256 exp instr/wave/apply. Fix: af = exp2(min(t', 32768*t')) —
// t'>=0 passes through, t'<0 drives arg below -24 -> fp16 exp2 underflows to
// exact 0. Replaces the 4-op clamp chain with 2 ops: pk instrs 1024 -> 768.

#define NN 2048
#define NPAIR 16

typedef _Float16 half8 __attribute__((ext_vector_type(8)));
typedef _Float16 f16x2 __attribute__((ext_vector_type(2)));
typedef float f32x4 __attribute__((ext_vector_type(4)));

extern "C" __device__ f16x2 __ocml_exp2_2f16(f16x2);   // packed v_exp_f16

#define C2F 0.28853900817779268f   //  0.2 * log2(e)
#define CWF -0.14426950408889634f  // -0.1 * log2(e)
#define NL2T 3.3219280948873623f   // -log2(0.1); qi' = qi + NL2T

// ---- init: Xs fp32 [p][i][{x,y,z,q}]; XT fp16 [p][16][2048], row3 = ones ----
__global__ __launch_bounds__(256) void init_k(const float* __restrict__ pc,
                                              const float* __restrict__ alphas,
                                              float* __restrict__ Xs,
                                              _Float16* __restrict__ XT) {
    int gid = blockIdx.x * 256 + threadIdx.x;
    if (gid >= NPAIR * NN) return;
    int p = gid >> 11, i = gid & (NN - 1);
    int b = p >> 2, k = p & 3;
    const float* pcr = pc + ((size_t)b * NN + i) * 3;
    const float* al  = alphas + k * 3;
    float x = pcr[0] * al[0], y = pcr[1] * al[1], z = pcr[2] * al[2];
    float4 o; o.x = x; o.y = y; o.z = z; o.w = CWF * (x * x + y * y + z * z);
    ((float4*)Xs)[gid] = o;
    _Float16* xt = XT + (size_t)p * 16 * NN + i;
    xt[0 * NN] = (_Float16)x;
    xt[1 * NN] = (_Float16)y;
    xt[2 * NN] = (_Float16)z;
    xt[3 * NN] = (_Float16)1.0f;          // ones column -> deg via MFMA
#pragma unroll
    for (int n = 4; n < 16; ++n) xt[n * NN] = (_Float16)0.f;
}

// ---- pack_k: Xp16[p][e] = {x2,y2,z2,q2} fp16 pairs of rows (2e, 2e+1) ----
__global__ __launch_bounds__(256) void pack_k(const float* __restrict__ Xs,
                                              float* __restrict__ Xp) {
    int gid = blockIdx.x * 256 + threadIdx.x;      // p*1024 + e
    if (gid >= NPAIR * 1024) return;
    float4 a = ((const float4*)Xs)[2 * gid];
    float4 b = ((const float4*)Xs)[2 * gid + 1];
    union { f16x2 h[4]; float4 f; } o;
    o.h[0] = (f16x2){(_Float16)a.x, (_Float16)b.x};
    o.h[1] = (f16x2){(_Float16)a.y, (_Float16)b.y};
    o.h[2] = (f16x2){(_Float16)a.z, (_Float16)b.z};
    o.h[3] = (f16x2){(_Float16)a.w, (_Float16)b.w};
    ((float4*)Xp)[gid] = o.f;
}

// ---- fused apply: Ct = f16(0.5*Bt + ihd (x) (W@Bt^T)^T), W recomputed ----
// block = 512 thr = 8 waves (K-chunk 256 each); lane owns 4 m-subtiles.
// Fragments hold 10*w; epilogue uses 0.1*ih (exact fold via 2^3.32=10).
template<bool FIRST>
__global__ __launch_bounds__(512, 4) void fused_apply_k(const float* __restrict__ Xs,
                                                        const float* __restrict__ Xp,
                                                        float* __restrict__ ihd,
                                                        const _Float16* __restrict__ Bt,
                                                        _Float16* __restrict__ Ct,
                                                        float* __restrict__ lvl,
                                                        int t) {
    __shared__ __align__(16) float smem[8192];     // 16KB packed X stage / 32KB red
    const int tid  = threadIdx.x;
    const int lane = tid & 63;
    const int wv   = tid >> 6;                     // K-group 0..7
    const int p    = blockIdx.y;
    const int m0   = blockIdx.x * 64;
    const int idx16 = lane & 15, quad = lane >> 4;

    // stage packed X[p] into LDS: 1024 float4 entries (2 per thread)
    {
        const float4* src = (const float4*)(Xp + (size_t)p * 1024 * 4);
        float4* dst = (float4*)smem;
        dst[tid]       = src[tid];
        dst[tid + 512] = src[tid + 512];
    }
    __syncthreads();

    // per-lane row constants (fp16 broadcast pairs), from fp32 Xs
    f16x2 qi2[4], xx2[4], xy2[4], xz2[4];
#pragma unroll
    for (int s = 0; s < 4; ++s) {
        float4 v = *(const float4*)(Xs + ((size_t)p * NN + m0 + s * 16 + idx16) * 4);
        _Float16 q = (_Float16)(v.w + NL2T);
        _Float16 x = (_Float16)(C2F * v.x);
        _Float16 y = (_Float16)(C2F * v.y);
        _Float16 z = (_Float16)(C2F * v.z);
        qi2[s] = (f16x2){q, q};
        xx2[s] = (f16x2){x, x};
        xy2[s] = (f16x2){y, y};
        xz2[s] = (f16x2){z, z};
    }
    const f16x2 SC2 = (f16x2){(_Float16)32768.f, (_Float16)32768.f};

    const _Float16* bp = Bt + ((size_t)p * 16 + idx16) * NN + wv * 256 + quad * 8;
    f32x4 acc[4] = {{0.f,0.f,0.f,0.f},{0.f,0.f,0.f,0.f},
                    {0.f,0.f,0.f,0.f},{0.f,0.f,0.f,0.f}};

    for (int kc = 0; kc < 8; ++kc) {
        const int pb = wv * 128 + kc * 16 + quad * 4;  // j-pair entry base
        half8 bf = *(const half8*)(bp + kc * 32);
        union { f16x2 h2[4]; half8 h8; } af[4];
#pragma unroll
        for (int jp = 0; jp < 4; ++jp) {
            union { float4 f; f16x2 h[4]; } e;
            e.f = ((const float4*)smem)[pb + jp];      // {x2,y2,z2,q2} for 2 j
#pragma unroll
            for (int s = 0; s < 4; ++s) {
                f16x2 tv = qi2[s] + e.h[3];
                tv = __builtin_elementwise_fma(xx2[s], e.h[0], tv);
                tv = __builtin_elementwise_fma(xy2[s], e.h[1], tv);
                tv = __builtin_elementwise_fma(xz2[s], e.h[2], tv);
                // threshold folded into exp arg: t'<0 -> arg <= -24 -> exp2 = 0
                f16x2 u = __builtin_elementwise_min(tv, tv * SC2);
                af[s].h2[jp] = __ocml_exp2_2f16(u);    // = 10*w (2^3.32 fold)
            }
        }
#pragma unroll
        for (int s = 0; s < 4; ++s)
            acc[s] = __builtin_amdgcn_mfma_f32_16x16x32_f16(af[s].h8, bf, acc[s], 0, 0, 0);
    }

    // cross-wave K-reduce: red[kg 8][s 4][256] aliased over stage
    __syncthreads();
#pragma unroll
    for (int s = 0; s < 4; ++s)
        *(f32x4*)&smem[wv * 1024 + s * 256 + lane * 4] = acc[s];
    __syncthreads();

    // 2 outputs/thread: o -> n = o&15, rloc = o>>4
    const float* ihp = ihd + p * NN;
#pragma unroll
    for (int oo = 0; oo < 2; ++oo) {
        const int o = tid + oo * 512;
        const int n = o & 15, rloc = o >> 4;
        const int s = rloc >> 4, mloc = rloc & 15;
        const int base = s * 256 + (mloc >> 2) * 64 + (mloc & 3);
        float sum = 0.f;                               // = 10 * (W@B) element
#pragma unroll
        for (int g = 0; g < 8; ++g) sum += smem[g * 1024 + base + n * 4];
        const int row = m0 + rloc;
        float ihEff;
        if (FIRST) {
            float deg10 = 0.f;                         // = 10 * deg
#pragma unroll
            for (int g = 0; g < 8; ++g) deg10 += smem[g * 1024 + base + 12];
            float ih = 5.0f / deg10;                   // = 0.5/deg
            if (n == 3) ihd[p * NN + row] = ih;
            ihEff = 0.1f * ih;
        } else {
            ihEff = 0.1f * ihp[row];
        }
        float cv = (float)Bt[((size_t)p * 16 + n) * NN + row];
        float out = 0.5f * cv + ihEff * sum;
        Ct[((size_t)p * 16 + n) * NN + row] = (_Float16)out;
        if (lvl) lvl[(((size_t)p * 5 + t) * 16 + n) * NN + row] = out;
    }
}

// ---- build UT fp16 [p][16][2048]: rows 0-11 = |psi_0..3 X|, 12-15 = 0 ----
__global__ __launch_bounds__(256) void buildU_k(const float* __restrict__ Xs,
                                                const float* __restrict__ LT1,
                                                _Float16* __restrict__ UT) {
    int p = blockIdx.y;
    int m = blockIdx.x * 256 + threadIdx.x;
    const float* lp = LT1 + (size_t)p * 5 * 16 * NN;
    float4 xr = ((const float4*)Xs)[p * NN + m];
    float prev[3] = {xr.x, xr.y, xr.z};
    _Float16* ut = UT + (size_t)p * 16 * NN + m;
#pragma unroll
    for (int jw = 0; jw < 4; ++jw) {
#pragma unroll
        for (int c = 0; c < 3; ++c) {
            float nx = lp[((size_t)jw * 16 + c) * NN + m];
            ut[(3 * jw + c) * NN] = (_Float16)fabsf(prev[c] - nx);
            prev[c] = nx;
        }
    }
#pragma unroll
    for (int n = 12; n < 16; ++n) ut[n * NN] = (_Float16)0.f;
}

// ---- final mean over N of 48 features (levels [p][t][n][m]) ----
__global__ __launch_bounds__(64) void reduce_k(const float* __restrict__ Xs,
                                               const float* __restrict__ LT1,
                                               const float* __restrict__ LT2,
                                               float* __restrict__ out) {
    int f = blockIdx.x, p = blockIdx.y, lane = threadIdx.x;
    const float* l1 = LT1 + (size_t)p * 5 * 16 * NN;
    const float* l2 = LT2 + (size_t)p * 5 * 16 * NN;
    float s = 0.f;
    for (int m = lane; m < NN; m += 64) {
        float v;
        if (f < 3) {
            v = l1[((size_t)4 * 16 + f) * NN + m];
        } else if (f < 18) {
            int j = (f - 3) / 3, c = (f - 3) % 3;
            float a = (j == 0) ? Xs[((size_t)p * NN + m) * 4 + c]
                               : l1[((size_t)(j - 1) * 16 + c) * NN + m];
            float b = l1[((size_t)j * 16 + c) * NN + m];
            v = fabsf(a - b);
        } else {
            int gg = f - 18, j2, uc;
            if (gg < 3)       { j2 = 1; uc = gg; }
            else if (gg < 9)  { j2 = 2; uc = gg - 3; }
            else if (gg < 18) { j2 = 3; uc = gg - 9; }
            else              { j2 = 4; uc = gg - 18; }
            v = fabsf(l2[((size_t)(j2 - 1) * 16 + uc) * NN + m]
                    - l2[((size_t)j2 * 16 + uc) * NN + m]);
        }
        s += v;
    }
#pragma unroll
    for (int off = 32; off > 0; off >>= 1) s += __shfl_down(s, off, 64);
    if (lane == 0) out[p * 48 + f] = s * (1.0f / NN);
}

extern "C" void kernel_launch(void* const* d_in, const int* in_sizes, int n_in,
                              void* d_out, int out_size, void* d_ws, size_t ws_size,
                              hipStream_t stream) {
    const float* pc     = (const float*)d_in[0];
    const float* alphas = (const float*)d_in[1];
    float* outp = (float*)d_out;

    char* base = (char*)d_ws;
    size_t off = 0;
    auto carve = [&](size_t bytes) -> void* {
        void* r = base + off;
        off = (off + bytes + 255) & ~(size_t)255;
        return r;
    };
    float*     Xs  = (float*)carve((size_t)NPAIR * NN * 4 * sizeof(float));
    float*     Xp  = (float*)carve((size_t)NPAIR * 1024 * 4 * sizeof(float));
    float*     ihd = (float*)carve((size_t)NPAIR * NN * sizeof(float));
    _Float16*  XT  = (_Float16*)carve((size_t)NPAIR * 16 * NN * 2);
    _Float16*  UT  = (_Float16*)carve((size_t)NPAIR * 16 * NN * 2);
    _Float16*  pA  = (_Float16*)carve((size_t)NPAIR * 16 * NN * 2);
    _Float16*  pB  = (_Float16*)carve((size_t)NPAIR * 16 * NN * 2);
    float*     LT1 = (float*)carve((size_t)NPAIR * 5 * 16 * NN * sizeof(float));
    float*     LT2 = (float*)carve((size_t)NPAIR * 5 * 16 * NN * sizeof(float));

    dim3 gridA(NN / 64, NPAIR);   // 32 x 16 = 512 blocks

    init_k<<<dim3((NPAIR * NN) / 256), 256, 0, stream>>>(pc, alphas, Xs, XT);
    pack_k<<<dim3((NPAIR * 1024) / 256), 256, 0, stream>>>(Xs, Xp);

    // bank 1: B = XT (col3 = ones -> apply#1 computes deg/ihd itself)
    {
        const _Float16* cur = XT;
        int slot = 0;
        for (int step = 1; step <= 16; ++step) {
            bool sv = (step == 1 || step == 2 || step == 4 || step == 8 || step == 16);
            _Float16* o = (cur == pA) ? pB : pA;
            float* lv = sv ? LT1 : nullptr;
            if (step == 1)
                fused_apply_k<true><<<gridA, 512, 0, stream>>>(Xs, Xp, ihd, cur, o, lv, slot);
            else
                fused_apply_k<false><<<gridA, 512, 0, stream>>>(Xs, Xp, ihd, cur, o, lv, slot);
            if (sv) ++slot;
            cur = o;
        }
    }

    buildU_k<<<dim3(NN / 256, NPAIR), 256, 0, stream>>>(Xs, LT1, UT);

    // bank 2: B = UT
    {
        const _Float16* cur = UT;
        int slot = 0;
        for (int step = 1; step <= 16; ++step) {
            bool sv = (step == 1 || step == 2 || step == 4 || step == 8 || step == 16);
            _Float16* o = (cur == pA) ? pB : pA;
            fused_apply_k<false><<<gridA, 512, 0, stream>>>(Xs, Xp, ihd, cur, o,
                                                            sv ? LT2 : nullptr, slot);
            if (sv) ++slot;
            cur = o;
        }
    }

    reduce_k<<<dim3(48, NPAIR), 64, 0, stream>>>(Xs, LT1, LT2, outp);
}